// Round 7
// baseline (157.340 us; speedup 1.0000x reference)
//
#include <hip/hip_runtime.h>
#include <hip/hip_bf16.h>

#define NB 8
#define NC 256
#define NL 2048
#define ND 128
#define NROWS (NB * NL)                   // 16384 Q rows
#define QKV_ELEMS ((size_t)NB * NL * ND)  // 2,097,152
#define W_ELEMS (ND * NC)                 // 32,768
#define XS_STRIDE 264                     // 256 + 8 shorts pad: 16B-aligned rows

typedef __attribute__((ext_vector_type(8))) short bf16x8;
typedef __attribute__((ext_vector_type(4))) float f32x4;
typedef __attribute__((ext_vector_type(16))) float f32x16;

__device__ __forceinline__ unsigned short f2bf(float f) {
    union { float f; unsigned u; } v; v.f = f;
    unsigned r = v.u + 0x7fffu + ((v.u >> 16) & 1u);
    return (unsigned short)(r >> 16);
}

// async global->LDS, 16 B per lane; LDS dest = uniform base + lane*16
__device__ __forceinline__ void load_lds16(const unsigned short* g, unsigned short* l) {
    __builtin_amdgcn_global_load_lds((const __attribute__((address_space(1))) unsigned int*)g,
                                     (__attribute__((address_space(3))) unsigned int*)l, 16, 0, 0);
}

// cast Wq|Wk|Wv -> contiguous bf16 buffer [3][D][C]
__global__ void cast_w3(const float* __restrict__ wq, const float* __restrict__ wk,
                        const float* __restrict__ wv, unsigned short* __restrict__ dst) {
    int i = blockIdx.x * blockDim.x + threadIdx.x;
    if (i >= 3 * W_ELEMS) return;
    int sel = i / W_ELEMS, off = i - sel * W_ELEMS;
    const float* s = (sel == 0) ? wq : (sel == 1) ? wk : wv;
    dst[i] = f2bf(s[off]);
}

// Fused transpose+cast+projection. Reads x [b][C][L] f32 directly.
// blockIdx.x: b*32 + l-tile (64 l's). blockIdx.y: 0 = Q (from xi); 1 = K and V (from xo, staged once).
__global__ __launch_bounds__(256, 4) void proj_direct(const float* __restrict__ xi,
                                                      const float* __restrict__ xo,
                                                      const unsigned short* __restrict__ Wall,
                                                      const float* __restrict__ bq,
                                                      const float* __restrict__ bk,
                                                      const float* __restrict__ bv,
                                                      unsigned short* __restrict__ Qb,
                                                      unsigned short* __restrict__ Kb,
                                                      unsigned short* __restrict__ Vtb) {
    __shared__ unsigned short xs[64 * XS_STRIDE];  // x^T tile [64 l][256 c] bf16, 33 KB
    int b = blockIdx.x >> 5, lt = blockIdx.x & 31, l0 = lt * 64;
    int y = blockIdx.y;
    int wave = threadIdx.x >> 6, lane = threadIdx.x & 63;
    int ln = lane & 15, quad = lane >> 4;

    // ---- stage: xs[l][c] = bf16(x[c][l0+l]); float4 loads, 4-in-flight groups ----
    const float* xsrc = (y == 0 ? xi : xo) + (size_t)b * NC * NL + l0;
    int l4 = (lane & 15) * 4;
    int cr0 = wave * 4 + (lane >> 4);
    #pragma unroll
    for (int g = 0; g < 4; g++) {
        float4 r[4];
        #pragma unroll
        for (int gi = 0; gi < 4; gi++) {
            int c = cr0 + (g * 4 + gi) * 16;
            r[gi] = *reinterpret_cast<const float4*>(xsrc + (size_t)c * NL + l4);
        }
        #pragma unroll
        for (int gi = 0; gi < 4; gi++) {
            int c = cr0 + (g * 4 + gi) * 16;
            xs[(l4 + 0) * XS_STRIDE + c] = f2bf(r[gi].x);
            xs[(l4 + 1) * XS_STRIDE + c] = f2bf(r[gi].y);
            xs[(l4 + 2) * XS_STRIDE + c] = f2bf(r[gi].z);
            xs[(l4 + 3) * XS_STRIDE + c] = f2bf(r[gi].w);
        }
    }
    __syncthreads();

    // ---- Q or K: out[l][d] = sum_c xs[l][c] * W[d][c] + bias[d], [B,L,D] ----
    {
        const unsigned short* Wb = Wall + (size_t)y * W_ELEMS;  // y=0 -> Wq, y=1 -> Wk
        const float* bias = y ? bk : bq;
        unsigned short* out = y ? Kb : Qb;
        int m0w = wave * 16;
        f32x4 acc[8] = {};
        #pragma unroll
        for (int s = 0; s < 8; s++) {
            bf16x8 af = *reinterpret_cast<const bf16x8*>(xs + (m0w + ln) * XS_STRIDE + s * 32 + quad * 8);
            #pragma unroll
            for (int t = 0; t < 8; t++) {
                bf16x8 bfr = *reinterpret_cast<const bf16x8*>(Wb + (size_t)(t * 16 + ln) * NC + s * 32 + quad * 8);
                acc[t] = __builtin_amdgcn_mfma_f32_16x16x32_bf16(af, bfr, acc[t], 0, 0, 0);
            }
        }
        #pragma unroll
        for (int t = 0; t < 8; t++) {
            int col = t * 16 + ln;
            float bi = bias[col];
            #pragma unroll
            for (int r = 0; r < 4; r++)
                out[(size_t)(b * NL + l0 + m0w + quad * 4 + r) * ND + col] = f2bf(acc[t][r] + bi);
        }
    }
    // ---- V (y==1 only, reuses staged xo tile): vt[d][l] = sum_c W[d][c]*xs[l][c] + bv[d], [B,D,L] ----
    if (y == 1) {
        const unsigned short* Wb = Wall + 2 * (size_t)W_ELEMS;
        f32x4 acc[2][4] = {};
        #pragma unroll
        for (int s = 0; s < 8; s++) {
            bf16x8 wf0 = *reinterpret_cast<const bf16x8*>(Wb + (size_t)(wave * 32 + ln) * NC + s * 32 + quad * 8);
            bf16x8 wf1 = *reinterpret_cast<const bf16x8*>(Wb + (size_t)(wave * 32 + 16 + ln) * NC + s * 32 + quad * 8);
            #pragma unroll
            for (int t = 0; t < 4; t++) {
                bf16x8 xb = *reinterpret_cast<const bf16x8*>(xs + (t * 16 + ln) * XS_STRIDE + s * 32 + quad * 8);
                acc[0][t] = __builtin_amdgcn_mfma_f32_16x16x32_bf16(wf0, xb, acc[0][t], 0, 0, 0);
                acc[1][t] = __builtin_amdgcn_mfma_f32_16x16x32_bf16(wf1, xb, acc[1][t], 0, 0, 0);
            }
        }
        #pragma unroll
        for (int u = 0; u < 2; u++)
            #pragma unroll
            for (int t = 0; t < 4; t++)
                #pragma unroll
                for (int r = 0; r < 4; r++) {
                    int d = wave * 32 + u * 16 + quad * 4 + r;
                    Vtb[(size_t)(b * ND + d) * NL + l0 + t * 16 + ln] = f2bf(acc[u][t][r] + bv[d]);
                }
    }
}

// split-KV flash attention, 32x32 MFMA, 128-q blocks (32 q per wave), fixed-M softmax.
// S^T = K Q^T (two 32x32 C-tiles per wave), O^T = V^T P^T (four 32x32 C-tiles).
// kbuf [64 kv][128 d]: chunk slot j of row r holds global chunk j^(r&15)  (global_load_lds).
// vbuf [128 d][64 kv] padded stride 72, slot j^(d&7)                      (manual staging).
// pbuf per-wave [32 q][64 kv] padded stride 72, slot j^(q&7).
// LDS = 16K + 18K + 18K = 53,248 B -> 3 blocks/CU cap; grid 512 -> 2 resident.
__global__ __launch_bounds__(256, 2) void flash_attn_split(const unsigned short* __restrict__ Q,
                                                           const unsigned short* __restrict__ K,
                                                           const unsigned short* __restrict__ Vt,
                                                           float* __restrict__ Opart,
                                                           float* __restrict__ lbuf,
                                                           int kvlen) {
    __shared__ unsigned short kbuf[64 * 128];
    __shared__ unsigned short vbuf[128 * 72];
    __shared__ unsigned short pbuf[4][32 * 72];
    int b = blockIdx.x >> 4, qt = blockIdx.x & 15;
    int sp = blockIdx.y;
    int kv0 = sp * kvlen;
    int wave = threadIdx.x >> 6, lane = threadIdx.x & 63;
    int l31 = lane & 31, h = lane >> 5;
    int m0 = qt * 128 + wave * 32;
    const float scale = 0.08838834764831845f * 1.4426950408889634f;  // 1/sqrt(128) * log2(e)

    // Q B-frags: lane holds Q[q = m0+l31][k = s*16 + h*8 + j]
    bf16x8 qf[8];
    const unsigned short* qrow = Q + (size_t)(b * NL + m0 + l31) * ND + h * 8;
    #pragma unroll
    for (int s = 0; s < 8; s++) qf[s] = *reinterpret_cast<const bf16x8*>(qrow + s * 16);

    float lsum = 0.f;
    f32x16 o_acc[4] = {};

    unsigned short* pw = pbuf[wave];
    const unsigned short* kg = K + (size_t)b * NL * ND;
    const unsigned short* vg = Vt + (size_t)b * ND * NL;

    int krt = wave * 16 + (lane >> 4);
    int kjs_lane = lane & 15;
    int vd = wave * 32 + (lane >> 3);   // +i*8 : V d-row (d&7 == lane>>3)
    int vc = lane & 7;

    for (int kt = kv0; kt < kv0 + kvlen; kt += 64) {
        // ---- stage K tile (async, 4 instrs/wave) ----
        #pragma unroll
        for (int i = 0; i < 4; i++) {
            int rt = krt + i * 4;
            int js = kjs_lane ^ (rt & 15);
            load_lds16(kg + (size_t)(kt + rt) * ND + js * 8, kbuf + (wave * 16 + i * 4) * 128);
        }
        // ---- stage V tile (manual: padded rows, 4 loads then 4 LDS writes) ----
        {
            bf16x8 vld[4];
            #pragma unroll
            for (int i = 0; i < 4; i++)
                vld[i] = *reinterpret_cast<const bf16x8*>(vg + (size_t)(vd + i * 8) * NL + kt + vc * 8);
            #pragma unroll
            for (int i = 0; i < 4; i++) {
                int d = vd + i * 8;
                int slot = vc ^ (d & 7);
                *reinterpret_cast<bf16x8*>(vbuf + d * 72 + slot * 8) = vld[i];
            }
        }
        __syncthreads();

        // ---- S^T = K Q^T : tile tt covers kv = tt*32 + C-rows, q col = l31 ----
        f32x16 sacc[2] = {};
        #pragma unroll
        for (int tt = 0; tt < 2; tt++) {
            const unsigned short* krow_p = kbuf + (tt * 32 + l31) * 128;
            #pragma unroll
            for (int s = 0; s < 8; s++) {
                bf16x8 kf = *reinterpret_cast<const bf16x8*>(krow_p + (((s * 2 + h) ^ (lane & 15)) << 3));
                sacc[tt] = __builtin_amdgcn_mfma_f32_32x32x16_bf16(kf, qf[s], sacc[tt], 0, 0, 0);
            }
        }
        // ---- fixed-M softmax + P^T pack into per-wave LDS ----
        #pragma unroll
        for (int tt = 0; tt < 2; tt++) {
            #pragma unroll
            for (int g = 0; g < 4; g++) {
                #pragma unroll
                for (int rr = 0; rr < 4; rr++) {
                    float pv = __builtin_exp2f(sacc[tt][g * 4 + rr] * scale);
                    lsum += pv;
                    int klo = h * 4 + rr;          // kv & 7
                    int chunk = tt * 4 + g;        // kv >> 3
                    pw[l31 * 72 + ((chunk ^ (l31 & 7)) << 3) + klo] = f2bf(pv);
                }
            }
        }
        // ---- P B-frags: lane holds P[q=l31][kv = step*16 + h*8 + j] ----
        bf16x8 pb[4];
        #pragma unroll
        for (int step = 0; step < 4; step++)
            pb[step] = *reinterpret_cast<const bf16x8*>(pw + l31 * 72 + (((step * 2 + h) ^ (l31 & 7)) << 3));
        // ---- O^T += V^T P^T : tile dt covers d = dt*32 + C-rows, q col = l31 ----
        #pragma unroll
        for (int dt = 0; dt < 4; dt++) {
            const unsigned short* vrow = vbuf + (dt * 32 + l31) * 72;
            #pragma unroll
            for (int step = 0; step < 4; step++) {
                bf16x8 vf = *reinterpret_cast<const bf16x8*>(vrow + (((step * 2 + h) ^ (lane & 7)) << 3));
                o_acc[dt] = __builtin_amdgcn_mfma_f32_32x32x16_bf16(vf, pb[step], o_acc[dt], 0, 0, 0);
            }
        }
        __syncthreads();
    }
    // lanes L and L+32 share q; combine their kv-halves
    lsum += __shfl_xor(lsum, 32);

    float* op = Opart + (size_t)sp * QKV_ELEMS;
    int qrow_g = b * NL + m0 + l31;
    if (lane < 32) lbuf[(size_t)sp * NROWS + qrow_g] = lsum;
    // O^T C-layout: d = dt*32 + (reg&3) + 8*(reg>>2) + 4*h, q = l31 -> 16 f32x4 stores
    #pragma unroll
    for (int dt = 0; dt < 4; dt++) {
        #pragma unroll
        for (int g = 0; g < 4; g++) {
            f32x4 v4 = { o_acc[dt][g * 4 + 0], o_acc[dt][g * 4 + 1],
                         o_acc[dt][g * 4 + 2], o_acc[dt][g * 4 + 3] };
            *reinterpret_cast<f32x4*>(op + (size_t)qrow_g * ND + dt * 32 + g * 8 + h * 4) = v4;
        }
    }
}

// merge S split partials (fixed-M: plain sums) -> normalized out (f32)
__global__ __launch_bounds__(256) void attn_merge(const float* __restrict__ Opart,
                                                  const float* __restrict__ lbuf,
                                                  float* __restrict__ out, int S) {
    int idx = blockIdx.x * 256 + threadIdx.x;   // one float4 group
    int row = idx >> 5;
    int dg = (idx & 31) * 4;
    float L = 0.f;
    float4 acc = make_float4(0.f, 0.f, 0.f, 0.f);
    for (int s = 0; s < S; s++) {
        L += lbuf[(size_t)s * NROWS + row];
        float4 o = *reinterpret_cast<const float4*>(Opart + (size_t)s * QKV_ELEMS + (size_t)row * ND + dg);
        acc.x += o.x; acc.y += o.y; acc.z += o.z; acc.w += o.w;
    }
    float inv = 1.0f / L;
    float4 res = make_float4(acc.x * inv, acc.y * inv, acc.z * inv, acc.w * inv);
    *reinterpret_cast<float4*>(out + (size_t)row * ND + dg) = res;
}

extern "C" void kernel_launch(void* const* d_in, const int* in_sizes, int n_in,
                              void* d_out, int out_size, void* d_ws, size_t ws_size,
                              hipStream_t stream) {
    const float* x_inner = (const float*)d_in[0];
    const float* x_outer = (const float*)d_in[1];
    const float* Wq = (const float*)d_in[2];
    const float* bq = (const float*)d_in[3];
    const float* Wk = (const float*)d_in[4];
    const float* bk = (const float*)d_in[5];
    const float* Wv = (const float*)d_in[6];
    const float* bv = (const float*)d_in[7];
    float* out = (float*)d_out;

    // workspace: [ union { Opart, l } ][ Qb ][ Kb ][ Vtb ][ Wall ]
    size_t need4 = 34078720u + 3 * QKV_ELEMS * 2 + 3 * W_ELEMS * 2;
    int S = (ws_size >= need4) ? 4 : 2;
    size_t union_bytes = (S == 4) ? 34078720u : 17039360u;

    char* w = (char*)d_ws;
    float* Opart = (float*)w;                                // [S][B*L][D]
    float* lbuf = (float*)(w + (size_t)S * QKV_ELEMS * 4);   // [S][B*L]
    unsigned short* Qb = (unsigned short*)(w + union_bytes); // [B,L,D]
    unsigned short* Kb = Qb + QKV_ELEMS;                     // [B,L,D]
    unsigned short* Vtb = Kb + QKV_ELEMS;                    // [B,D,L]
    unsigned short* Wall = Vtb + QKV_ELEMS;                  // [3][D][C]

    cast_w3<<<(3 * W_ELEMS + 255) / 256, 256, 0, stream>>>(Wq, Wk, Wv, Wall);
    dim3 pgrid(NB * (NL / 64), 2);
    proj_direct<<<pgrid, 256, 0, stream>>>(x_inner, x_outer, Wall, bq, bk, bv, Qb, Kb, Vtb);
    dim3 fgrid(NB * (NL / 128), S);
    flash_attn_split<<<fgrid, 256, 0, stream>>>(Qb, Kb, Vtb, Opart, lbuf, NL / S);
    attn_merge<<<(NROWS * ND / 4 + 255) / 256, 256, 0, stream>>>(Opart, lbuf, out, S);
}

// Round 8
// 152.152 us; speedup vs baseline: 1.0341x; 1.0341x over previous
//
#include <hip/hip_runtime.h>
#include <hip/hip_bf16.h>

#define NB 8
#define NC 256
#define NL 2048
#define ND 128
#define NROWS (NB * NL)                   // 16384 Q rows
#define QKV_ELEMS ((size_t)NB * NL * ND)  // 2,097,152
#define W_ELEMS (ND * NC)                 // 32,768
#define XS_STRIDE 264                     // 256 + 8 shorts pad: 16B-aligned rows

typedef __attribute__((ext_vector_type(8))) short bf16x8;
typedef __attribute__((ext_vector_type(4))) float f32x4;
typedef __attribute__((ext_vector_type(16))) float f32x16;

__device__ __forceinline__ unsigned short f2bf(float f) {
    union { float f; unsigned u; } v; v.f = f;
    unsigned r = v.u + 0x7fffu + ((v.u >> 16) & 1u);
    return (unsigned short)(r >> 16);
}

// async global->LDS, 16 B per lane; LDS dest = uniform base + lane*16
__device__ __forceinline__ void load_lds16(const unsigned short* g, unsigned short* l) {
    __builtin_amdgcn_global_load_lds((const __attribute__((address_space(1))) unsigned int*)g,
                                     (__attribute__((address_space(3))) unsigned int*)l, 16, 0, 0);
}

// cast Wq|Wk|Wv -> contiguous bf16 buffer [3][D][C]
__global__ void cast_w3(const float* __restrict__ wq, const float* __restrict__ wk,
                        const float* __restrict__ wv, unsigned short* __restrict__ dst) {
    int i = blockIdx.x * blockDim.x + threadIdx.x;
    if (i >= 3 * W_ELEMS) return;
    int sel = i / W_ELEMS, off = i - sel * W_ELEMS;
    const float* s = (sel == 0) ? wq : (sel == 1) ? wk : wv;
    dst[i] = f2bf(s[off]);
}

// Fused transpose+cast+projection. Reads x [b][C][L] f32 directly.
// blockIdx.x: b*32 + l-tile (64 l's). blockIdx.y: 0 = Q (from xi); 1 = K and V (from xo, staged once).
__global__ __launch_bounds__(256, 4) void proj_direct(const float* __restrict__ xi,
                                                      const float* __restrict__ xo,
                                                      const unsigned short* __restrict__ Wall,
                                                      const float* __restrict__ bq,
                                                      const float* __restrict__ bk,
                                                      const float* __restrict__ bv,
                                                      unsigned short* __restrict__ Qb,
                                                      unsigned short* __restrict__ Kb,
                                                      unsigned short* __restrict__ Vtb) {
    __shared__ unsigned short xs[64 * XS_STRIDE];  // x^T tile [64 l][256 c] bf16, 33 KB
    int b = blockIdx.x >> 5, lt = blockIdx.x & 31, l0 = lt * 64;
    int y = blockIdx.y;
    int wave = threadIdx.x >> 6, lane = threadIdx.x & 63;
    int ln = lane & 15, quad = lane >> 4;

    // ---- stage: xs[l][c] = bf16(x[c][l0+l]); float4 loads, 4-in-flight groups ----
    const float* xsrc = (y == 0 ? xi : xo) + (size_t)b * NC * NL + l0;
    int l4 = (lane & 15) * 4;
    int cr0 = wave * 4 + (lane >> 4);
    #pragma unroll
    for (int g = 0; g < 4; g++) {
        float4 r[4];
        #pragma unroll
        for (int gi = 0; gi < 4; gi++) {
            int c = cr0 + (g * 4 + gi) * 16;
            r[gi] = *reinterpret_cast<const float4*>(xsrc + (size_t)c * NL + l4);
        }
        #pragma unroll
        for (int gi = 0; gi < 4; gi++) {
            int c = cr0 + (g * 4 + gi) * 16;
            xs[(l4 + 0) * XS_STRIDE + c] = f2bf(r[gi].x);
            xs[(l4 + 1) * XS_STRIDE + c] = f2bf(r[gi].y);
            xs[(l4 + 2) * XS_STRIDE + c] = f2bf(r[gi].z);
            xs[(l4 + 3) * XS_STRIDE + c] = f2bf(r[gi].w);
        }
    }
    __syncthreads();

    // ---- Q or K: out[l][d] = sum_c xs[l][c] * W[d][c] + bias[d], [B,L,D] ----
    {
        const unsigned short* Wb = Wall + (size_t)y * W_ELEMS;  // y=0 -> Wq, y=1 -> Wk
        const float* bias = y ? bk : bq;
        unsigned short* out = y ? Kb : Qb;
        int m0w = wave * 16;
        f32x4 acc[8] = {};
        #pragma unroll
        for (int s = 0; s < 8; s++) {
            bf16x8 af = *reinterpret_cast<const bf16x8*>(xs + (m0w + ln) * XS_STRIDE + s * 32 + quad * 8);
            #pragma unroll
            for (int t = 0; t < 8; t++) {
                bf16x8 bfr = *reinterpret_cast<const bf16x8*>(Wb + (size_t)(t * 16 + ln) * NC + s * 32 + quad * 8);
                acc[t] = __builtin_amdgcn_mfma_f32_16x16x32_bf16(af, bfr, acc[t], 0, 0, 0);
            }
        }
        #pragma unroll
        for (int t = 0; t < 8; t++) {
            int col = t * 16 + ln;
            float bi = bias[col];
            #pragma unroll
            for (int r = 0; r < 4; r++)
                out[(size_t)(b * NL + l0 + m0w + quad * 4 + r) * ND + col] = f2bf(acc[t][r] + bi);
        }
    }
    // ---- V (y==1 only, reuses staged xo tile): vt[d][l] = sum_c W[d][c]*xs[l][c] + bv[d], [B,D,L] ----
    if (y == 1) {
        const unsigned short* Wb = Wall + 2 * (size_t)W_ELEMS;
        f32x4 acc[2][4] = {};
        #pragma unroll
        for (int s = 0; s < 8; s++) {
            bf16x8 wf0 = *reinterpret_cast<const bf16x8*>(Wb + (size_t)(wave * 32 + ln) * NC + s * 32 + quad * 8);
            bf16x8 wf1 = *reinterpret_cast<const bf16x8*>(Wb + (size_t)(wave * 32 + 16 + ln) * NC + s * 32 + quad * 8);
            #pragma unroll
            for (int t = 0; t < 4; t++) {
                bf16x8 xb = *reinterpret_cast<const bf16x8*>(xs + (t * 16 + ln) * XS_STRIDE + s * 32 + quad * 8);
                acc[0][t] = __builtin_amdgcn_mfma_f32_16x16x32_bf16(wf0, xb, acc[0][t], 0, 0, 0);
                acc[1][t] = __builtin_amdgcn_mfma_f32_16x16x32_bf16(wf1, xb, acc[1][t], 0, 0, 0);
            }
        }
        #pragma unroll
        for (int u = 0; u < 2; u++)
            #pragma unroll
            for (int t = 0; t < 4; t++)
                #pragma unroll
                for (int r = 0; r < 4; r++) {
                    int d = wave * 32 + u * 16 + quad * 4 + r;
                    Vtb[(size_t)(b * ND + d) * NL + l0 + t * 16 + ln] = f2bf(acc[u][t][r] + bv[d]);
                }
    }
}

// split-KV flash attention, 32x32 MFMA, 128-q blocks (32 q per wave), fixed-M softmax.
// S^T = K Q^T (two 32x32 C-tiles per wave), O^T = V^T P^T (four 32x32 C-tiles).
// All LDS tiles use stride-64-short rows (128 B == bank-neutral) + XOR-chunk swizzle:
//   kbuf [64 kv][128 d]: slot j of row r holds global chunk j^(r&15)  (global_load_lds)
//   vbuf [128 d][64 kv]: slot j of row d holds global chunk j^(d&7)   (global_load_lds)
//   pbuf per-wave [32 q][64 kv]: slot j of row q holds kv-chunk j^(q&7) (b64 packed writes)
// LDS = 16K + 16K + 16K = 49,152 B -> 3 blocks/CU cap; grid 512 -> 2 resident.
__global__ __launch_bounds__(256, 2) void flash_attn_split(const unsigned short* __restrict__ Q,
                                                           const unsigned short* __restrict__ K,
                                                           const unsigned short* __restrict__ Vt,
                                                           float* __restrict__ Opart,
                                                           float* __restrict__ lbuf,
                                                           int kvlen) {
    __shared__ unsigned short kbuf[64 * 128];
    __shared__ unsigned short vbuf[128 * 64];
    __shared__ unsigned short pbuf[4][32 * 64];
    int b = blockIdx.x >> 4, qt = blockIdx.x & 15;
    int sp = blockIdx.y;
    int kv0 = sp * kvlen;
    int wave = threadIdx.x >> 6, lane = threadIdx.x & 63;
    int l31 = lane & 31, h = lane >> 5;
    int m0 = qt * 128 + wave * 32;
    const float scale = 0.08838834764831845f * 1.4426950408889634f;  // 1/sqrt(128) * log2(e)

    // Q B-frags: lane holds Q[q = m0+l31][k = s*16 + h*8 + j]
    bf16x8 qf[8];
    const unsigned short* qrow = Q + (size_t)(b * NL + m0 + l31) * ND + h * 8;
    #pragma unroll
    for (int s = 0; s < 8; s++) qf[s] = *reinterpret_cast<const bf16x8*>(qrow + s * 16);

    float lsum = 0.f;
    f32x16 o_acc[4] = {};

    unsigned short* pw = pbuf[wave];
    const unsigned short* kg = K + (size_t)b * NL * ND;
    const unsigned short* vg = Vt + (size_t)b * ND * NL;

    int krt = wave * 16 + (lane >> 4);  // +i*4 : K row within tile
    int kjs_lane = lane & 15;
    int vdt = wave * 32 + (lane >> 3);  // +i*8 : V d-row
    int vjs_lane = lane & 7;

    for (int kt = kv0; kt < kv0 + kvlen; kt += 64) {
        // ---- stage K tile (async, 4 instrs/wave) ----
        #pragma unroll
        for (int i = 0; i < 4; i++) {
            int rt = krt + i * 4;
            int js = kjs_lane ^ (rt & 15);
            load_lds16(kg + (size_t)(kt + rt) * ND + js * 8, kbuf + (wave * 16 + i * 4) * 128);
        }
        // ---- stage V tile (async, 4 instrs/wave) ----
        #pragma unroll
        for (int i = 0; i < 4; i++) {
            int dt = vdt + i * 8;
            int js = vjs_lane ^ (dt & 7);
            load_lds16(vg + (size_t)dt * NL + kt + js * 8, vbuf + (wave * 32 + i * 8) * 64);
        }
        __syncthreads();

        // ---- S^T = K Q^T : tile tt covers kv = tt*32 + C-rows, q col = l31 ----
        f32x16 sacc[2] = {};
        #pragma unroll
        for (int tt = 0; tt < 2; tt++) {
            const unsigned short* krow_p = kbuf + (tt * 32 + l31) * 128;
            #pragma unroll
            for (int s = 0; s < 8; s++) {
                bf16x8 kf = *reinterpret_cast<const bf16x8*>(krow_p + (((s * 2 + h) ^ (lane & 15)) << 3));
                sacc[tt] = __builtin_amdgcn_mfma_f32_32x32x16_bf16(kf, qf[s], sacc[tt], 0, 0, 0);
            }
        }
        // ---- fixed-M softmax + P^T pack: one b64 write per (tt,g) chunk ----
        #pragma unroll
        for (int tt = 0; tt < 2; tt++) {
            #pragma unroll
            for (int g = 0; g < 4; g++) {
                float p0 = __builtin_exp2f(sacc[tt][g * 4 + 0] * scale);
                float p1 = __builtin_exp2f(sacc[tt][g * 4 + 1] * scale);
                float p2 = __builtin_exp2f(sacc[tt][g * 4 + 2] * scale);
                float p3 = __builtin_exp2f(sacc[tt][g * 4 + 3] * scale);
                lsum += (p0 + p1) + (p2 + p3);
                ushort4 o4 = { f2bf(p0), f2bf(p1), f2bf(p2), f2bf(p3) };
                int chunk = tt * 4 + g;        // kv >> 3 ; klo = h*4 + rr
                *reinterpret_cast<ushort4*>(pw + l31 * 64 + ((chunk ^ (l31 & 7)) << 3) + h * 4) = o4;
            }
        }
        // ---- P B-frags: lane holds P[q=l31][kv = step*16 + h*8 + j] ----
        bf16x8 pb[4];
        #pragma unroll
        for (int step = 0; step < 4; step++)
            pb[step] = *reinterpret_cast<const bf16x8*>(pw + l31 * 64 + (((step * 2 + h) ^ (l31 & 7)) << 3));
        // ---- O^T += V^T P^T : tile dt covers d = dt*32 + C-rows, q col = l31 ----
        #pragma unroll
        for (int dt = 0; dt < 4; dt++) {
            const unsigned short* vrow = vbuf + (dt * 32 + l31) * 64;
            #pragma unroll
            for (int step = 0; step < 4; step++) {
                bf16x8 vf = *reinterpret_cast<const bf16x8*>(vrow + (((step * 2 + h) ^ (l31 & 7)) << 3));
                o_acc[dt] = __builtin_amdgcn_mfma_f32_32x32x16_bf16(vf, pb[step], o_acc[dt], 0, 0, 0);
            }
        }
        __syncthreads();
    }
    // lanes L and L+32 share q; combine their kv-halves
    lsum += __shfl_xor(lsum, 32);

    float* op = Opart + (size_t)sp * QKV_ELEMS;
    int qrow_g = b * NL + m0 + l31;
    if (lane < 32) lbuf[(size_t)sp * NROWS + qrow_g] = lsum;
    // O^T C-layout: d = dt*32 + (reg&3) + 8*(reg>>2) + 4*h, q = l31 -> 16 f32x4 stores
    #pragma unroll
    for (int dt = 0; dt < 4; dt++) {
        #pragma unroll
        for (int g = 0; g < 4; g++) {
            f32x4 v4 = { o_acc[dt][g * 4 + 0], o_acc[dt][g * 4 + 1],
                         o_acc[dt][g * 4 + 2], o_acc[dt][g * 4 + 3] };
            *reinterpret_cast<f32x4*>(op + (size_t)qrow_g * ND + dt * 32 + g * 8 + h * 4) = v4;
        }
    }
}

// merge S split partials (fixed-M: plain sums) -> normalized out (f32)
__global__ __launch_bounds__(256) void attn_merge(const float* __restrict__ Opart,
                                                  const float* __restrict__ lbuf,
                                                  float* __restrict__ out, int S) {
    int idx = blockIdx.x * 256 + threadIdx.x;   // one float4 group
    int row = idx >> 5;
    int dg = (idx & 31) * 4;
    float L = 0.f;
    float4 acc = make_float4(0.f, 0.f, 0.f, 0.f);
    for (int s = 0; s < S; s++) {
        L += lbuf[(size_t)s * NROWS + row];
        float4 o = *reinterpret_cast<const float4*>(Opart + (size_t)s * QKV_ELEMS + (size_t)row * ND + dg);
        acc.x += o.x; acc.y += o.y; acc.z += o.z; acc.w += o.w;
    }
    float inv = 1.0f / L;
    float4 res = make_float4(acc.x * inv, acc.y * inv, acc.z * inv, acc.w * inv);
    *reinterpret_cast<float4*>(out + (size_t)row * ND + dg) = res;
}

extern "C" void kernel_launch(void* const* d_in, const int* in_sizes, int n_in,
                              void* d_out, int out_size, void* d_ws, size_t ws_size,
                              hipStream_t stream) {
    const float* x_inner = (const float*)d_in[0];
    const float* x_outer = (const float*)d_in[1];
    const float* Wq = (const float*)d_in[2];
    const float* bq = (const float*)d_in[3];
    const float* Wk = (const float*)d_in[4];
    const float* bk = (const float*)d_in[5];
    const float* Wv = (const float*)d_in[6];
    const float* bv = (const float*)d_in[7];
    float* out = (float*)d_out;

    // workspace: [ union { Opart, l } ][ Qb ][ Kb ][ Vtb ][ Wall ]
    size_t need4 = 34078720u + 3 * QKV_ELEMS * 2 + 3 * W_ELEMS * 2;
    int S = (ws_size >= need4) ? 4 : 2;
    size_t union_bytes = (S == 4) ? 34078720u : 17039360u;

    char* w = (char*)d_ws;
    float* Opart = (float*)w;                                // [S][B*L][D]
    float* lbuf = (float*)(w + (size_t)S * QKV_ELEMS * 4);   // [S][B*L]
    unsigned short* Qb = (unsigned short*)(w + union_bytes); // [B,L,D]
    unsigned short* Kb = Qb + QKV_ELEMS;                     // [B,L,D]
    unsigned short* Vtb = Kb + QKV_ELEMS;                    // [B,D,L]
    unsigned short* Wall = Vtb + QKV_ELEMS;                  // [3][D][C]

    cast_w3<<<(3 * W_ELEMS + 255) / 256, 256, 0, stream>>>(Wq, Wk, Wv, Wall);
    dim3 pgrid(NB * (NL / 64), 2);
    proj_direct<<<pgrid, 256, 0, stream>>>(x_inner, x_outer, Wall, bq, bk, bv, Qb, Kb, Vtb);
    dim3 fgrid(NB * (NL / 128), S);
    flash_attn_split<<<fgrid, 256, 0, stream>>>(Qb, Kb, Vtb, Opart, lbuf, NL / S);
    attn_merge<<<(NROWS * ND / 4 + 255) / 256, 256, 0, stream>>>(Opart, lbuf, out, S);
}

// Round 9
// 148.375 us; speedup vs baseline: 1.0604x; 1.0255x over previous
//
#include <hip/hip_runtime.h>
#include <hip/hip_bf16.h>

#define NB 8
#define NC 256
#define NL 2048
#define ND 128
#define NROWS (NB * NL)                   // 16384 Q rows
#define QKV_ELEMS ((size_t)NB * NL * ND)  // 2,097,152
#define W_ELEMS (ND * NC)                 // 32,768
#define XS_STRIDE 264                     // 256 + 8 shorts pad: 16B-aligned rows

typedef __attribute__((ext_vector_type(8))) short bf16x8;
typedef __attribute__((ext_vector_type(4))) float f32x4;
typedef __attribute__((ext_vector_type(16))) float f32x16;

__device__ __forceinline__ unsigned short f2bf(float f) {
    union { float f; unsigned u; } v; v.f = f;
    unsigned r = v.u + 0x7fffu + ((v.u >> 16) & 1u);
    return (unsigned short)(r >> 16);
}

// async global->LDS, 16 B per lane; LDS dest = uniform base + lane*16
__device__ __forceinline__ void load_lds16(const unsigned short* g, unsigned short* l) {
    __builtin_amdgcn_global_load_lds((const __attribute__((address_space(1))) unsigned int*)g,
                                     (__attribute__((address_space(3))) unsigned int*)l, 16, 0, 0);
}

// cast Wq|Wk|Wv -> contiguous bf16 buffer [3][D][C]
__global__ void cast_w3(const float* __restrict__ wq, const float* __restrict__ wk,
                        const float* __restrict__ wv, unsigned short* __restrict__ dst) {
    int i = blockIdx.x * blockDim.x + threadIdx.x;
    if (i >= 3 * W_ELEMS) return;
    int sel = i / W_ELEMS, off = i - sel * W_ELEMS;
    const float* s = (sel == 0) ? wq : (sel == 1) ? wk : wv;
    dst[i] = f2bf(s[off]);
}

// Fused transpose+cast+projection. Reads x [b][C][L] f32 directly.
// blockIdx.x: b*32 + l-tile (64 l's). blockIdx.y: 0 = Q (xi), 1 = K (xo), 2 = V (xo). Balanced.
__global__ __launch_bounds__(256, 4) void proj_direct(const float* __restrict__ xi,
                                                      const float* __restrict__ xo,
                                                      const unsigned short* __restrict__ Wall,
                                                      const float* __restrict__ bq,
                                                      const float* __restrict__ bk,
                                                      const float* __restrict__ bv,
                                                      unsigned short* __restrict__ Qb,
                                                      unsigned short* __restrict__ Kb,
                                                      unsigned short* __restrict__ Vtb) {
    __shared__ unsigned short xs[64 * XS_STRIDE];  // x^T tile [64 l][256 c] bf16, 33 KB
    int b = blockIdx.x >> 5, lt = blockIdx.x & 31, l0 = lt * 64;
    int y = blockIdx.y;
    int wave = threadIdx.x >> 6, lane = threadIdx.x & 63;
    int ln = lane & 15, quad = lane >> 4;

    // ---- stage: xs[l][c] = bf16(x[c][l0+l]); float4 loads, 4-in-flight groups ----
    const float* xsrc = (y == 0 ? xi : xo) + (size_t)b * NC * NL + l0;
    int l4 = (lane & 15) * 4;
    int cr0 = wave * 4 + (lane >> 4);
    #pragma unroll
    for (int g = 0; g < 4; g++) {
        float4 r[4];
        #pragma unroll
        for (int gi = 0; gi < 4; gi++) {
            int c = cr0 + (g * 4 + gi) * 16;
            r[gi] = *reinterpret_cast<const float4*>(xsrc + (size_t)c * NL + l4);
        }
        #pragma unroll
        for (int gi = 0; gi < 4; gi++) {
            int c = cr0 + (g * 4 + gi) * 16;
            xs[(l4 + 0) * XS_STRIDE + c] = f2bf(r[gi].x);
            xs[(l4 + 1) * XS_STRIDE + c] = f2bf(r[gi].y);
            xs[(l4 + 2) * XS_STRIDE + c] = f2bf(r[gi].z);
            xs[(l4 + 3) * XS_STRIDE + c] = f2bf(r[gi].w);
        }
    }
    __syncthreads();

    if (y < 2) {
        // ---- Q or K: out[l][d] = sum_c xs[l][c] * W[d][c] + bias[d], [B,L,D] ----
        const unsigned short* Wb = Wall + (size_t)y * W_ELEMS;  // y=0 -> Wq, y=1 -> Wk
        const float* bias = y ? bk : bq;
        unsigned short* out = y ? Kb : Qb;
        int m0w = wave * 16;
        f32x4 acc[8] = {};
        #pragma unroll
        for (int s = 0; s < 8; s++) {
            bf16x8 af = *reinterpret_cast<const bf16x8*>(xs + (m0w + ln) * XS_STRIDE + s * 32 + quad * 8);
            #pragma unroll
            for (int t = 0; t < 8; t++) {
                bf16x8 bfr = *reinterpret_cast<const bf16x8*>(Wb + (size_t)(t * 16 + ln) * NC + s * 32 + quad * 8);
                acc[t] = __builtin_amdgcn_mfma_f32_16x16x32_bf16(af, bfr, acc[t], 0, 0, 0);
            }
        }
        #pragma unroll
        for (int t = 0; t < 8; t++) {
            int col = t * 16 + ln;
            float bi = bias[col];
            #pragma unroll
            for (int r = 0; r < 4; r++)
                out[(size_t)(b * NL + l0 + m0w + quad * 4 + r) * ND + col] = f2bf(acc[t][r] + bi);
        }
    } else {
        // ---- V: vt[d][l] = sum_c W[d][c]*xs[l][c] + bv[d], [B,D,L] ----
        const unsigned short* Wb = Wall + 2 * (size_t)W_ELEMS;
        f32x4 acc[2][4] = {};
        #pragma unroll
        for (int s = 0; s < 8; s++) {
            bf16x8 wf0 = *reinterpret_cast<const bf16x8*>(Wb + (size_t)(wave * 32 + ln) * NC + s * 32 + quad * 8);
            bf16x8 wf1 = *reinterpret_cast<const bf16x8*>(Wb + (size_t)(wave * 32 + 16 + ln) * NC + s * 32 + quad * 8);
            #pragma unroll
            for (int t = 0; t < 4; t++) {
                bf16x8 xb = *reinterpret_cast<const bf16x8*>(xs + (t * 16 + ln) * XS_STRIDE + s * 32 + quad * 8);
                acc[0][t] = __builtin_amdgcn_mfma_f32_16x16x32_bf16(wf0, xb, acc[0][t], 0, 0, 0);
                acc[1][t] = __builtin_amdgcn_mfma_f32_16x16x32_bf16(wf1, xb, acc[1][t], 0, 0, 0);
            }
        }
        #pragma unroll
        for (int u = 0; u < 2; u++)
            #pragma unroll
            for (int t = 0; t < 4; t++)
                #pragma unroll
                for (int r = 0; r < 4; r++) {
                    int d = wave * 32 + u * 16 + quad * 4 + r;
                    Vtb[(size_t)(b * ND + d) * NL + l0 + t * 16 + ln] = f2bf(acc[u][t][r] + bv[d]);
                }
    }
}

// split-KV flash attention, 32x32 MFMA, 128-q blocks, fixed-M softmax, DOUBLE-BUFFERED K/V.
// Loop shape: barrier -> issue async prefetch(next) -> compute(cur). One barrier per iter;
// its vmcnt(0) drain covers loads that had the whole compute phase in flight.
//   kbuf[2] [64 kv][128 d]: slot j of row r holds global chunk j^(r&15)  (global_load_lds)
//   vbuf[2] [128 d][64 kv]: slot j of row d holds global chunk j^(d&7)   (global_load_lds)
//   pbuf per-wave [32 q][64 kv]: slot j of row q holds kv-chunk j^(q&7)  (b64 packed writes)
// LDS = 32K + 32K + 16K = 81,920 B -> 2 blocks/CU; grid 512 -> 2 resident (unchanged).
__global__ __launch_bounds__(256, 2) void flash_attn_split(const unsigned short* __restrict__ Q,
                                                           const unsigned short* __restrict__ K,
                                                           const unsigned short* __restrict__ Vt,
                                                           float* __restrict__ Opart,
                                                           float* __restrict__ lbuf,
                                                           int kvlen) {
    __shared__ unsigned short kbuf[2][64 * 128];
    __shared__ unsigned short vbuf[2][128 * 64];
    __shared__ unsigned short pbuf[4][32 * 64];
    int b = blockIdx.x >> 4, qt = blockIdx.x & 15;
    int sp = blockIdx.y;
    int kv0 = sp * kvlen;
    int wave = threadIdx.x >> 6, lane = threadIdx.x & 63;
    int l31 = lane & 31, h = lane >> 5;
    int m0 = qt * 128 + wave * 32;
    const float scale = 0.08838834764831845f * 1.4426950408889634f;  // 1/sqrt(128) * log2(e)

    // Q B-frags: lane holds Q[q = m0+l31][k = s*16 + h*8 + j]
    bf16x8 qf[8];
    const unsigned short* qrow = Q + (size_t)(b * NL + m0 + l31) * ND + h * 8;
    #pragma unroll
    for (int s = 0; s < 8; s++) qf[s] = *reinterpret_cast<const bf16x8*>(qrow + s * 16);

    float lsum = 0.f;
    f32x16 o_acc[4] = {};

    unsigned short* pw = pbuf[wave];
    const unsigned short* kg = K + (size_t)b * NL * ND;
    const unsigned short* vg = Vt + (size_t)b * ND * NL;

    int krt = wave * 16 + (lane >> 4);  // +i*4 : K row within tile
    int kjs = (lane & 15);
    int vdt = wave * 32 + (lane >> 3);  // +i*8 : V d-row
    int vjs = (lane & 7);

    // ---- prefetch tile 0 into buffer 0 ----
    {
        int kt = kv0;
        #pragma unroll
        for (int i = 0; i < 4; i++) {
            int rt = krt + i * 4;
            load_lds16(kg + (size_t)(kt + rt) * ND + (kjs ^ (rt & 15)) * 8, kbuf[0] + (wave * 16 + i * 4) * 128);
        }
        #pragma unroll
        for (int i = 0; i < 4; i++) {
            int dt = vdt + i * 8;
            load_lds16(vg + (size_t)dt * NL + kt + (vjs ^ (dt & 7)) * 8, vbuf[0] + (wave * 32 + i * 8) * 64);
        }
    }

    int niter = kvlen >> 6;
    for (int it = 0; it < niter; it++) {
        int cur = it & 1;
        __syncthreads();  // per-wave vmcnt drain + barrier: buffer `cur` ready, buffer `cur^1` free

        // ---- issue async prefetch of next tile into the other buffer ----
        if (it + 1 < niter) {
            int kt = kv0 + (it + 1) * 64;
            int nxt = cur ^ 1;
            #pragma unroll
            for (int i = 0; i < 4; i++) {
                int rt = krt + i * 4;
                load_lds16(kg + (size_t)(kt + rt) * ND + (kjs ^ (rt & 15)) * 8, kbuf[nxt] + (wave * 16 + i * 4) * 128);
            }
            #pragma unroll
            for (int i = 0; i < 4; i++) {
                int dt = vdt + i * 8;
                load_lds16(vg + (size_t)dt * NL + kt + (vjs ^ (dt & 7)) * 8, vbuf[nxt] + (wave * 32 + i * 8) * 64);
            }
        }
        const unsigned short* kb = kbuf[cur];
        const unsigned short* vb = vbuf[cur];

        // ---- S^T = K Q^T : tile tt covers kv = tt*32 + C-rows, q col = l31 ----
        f32x16 sacc[2] = {};
        #pragma unroll
        for (int tt = 0; tt < 2; tt++) {
            const unsigned short* krow_p = kb + (tt * 32 + l31) * 128;
            #pragma unroll
            for (int s = 0; s < 8; s++) {
                bf16x8 kf = *reinterpret_cast<const bf16x8*>(krow_p + (((s * 2 + h) ^ (lane & 15)) << 3));
                sacc[tt] = __builtin_amdgcn_mfma_f32_32x32x16_bf16(kf, qf[s], sacc[tt], 0, 0, 0);
            }
        }
        // ---- fixed-M softmax + P^T pack: one b64 write per (tt,g) chunk ----
        #pragma unroll
        for (int tt = 0; tt < 2; tt++) {
            #pragma unroll
            for (int g = 0; g < 4; g++) {
                float p0 = __builtin_exp2f(sacc[tt][g * 4 + 0] * scale);
                float p1 = __builtin_exp2f(sacc[tt][g * 4 + 1] * scale);
                float p2 = __builtin_exp2f(sacc[tt][g * 4 + 2] * scale);
                float p3 = __builtin_exp2f(sacc[tt][g * 4 + 3] * scale);
                lsum += (p0 + p1) + (p2 + p3);
                ushort4 o4 = { f2bf(p0), f2bf(p1), f2bf(p2), f2bf(p3) };
                int chunk = tt * 4 + g;        // kv >> 3 ; klo = h*4 + rr
                *reinterpret_cast<ushort4*>(pw + l31 * 64 + ((chunk ^ (l31 & 7)) << 3) + h * 4) = o4;
            }
        }
        // ---- P B-frags: lane holds P[q=l31][kv = step*16 + h*8 + j] ----
        bf16x8 pb[4];
        #pragma unroll
        for (int step = 0; step < 4; step++)
            pb[step] = *reinterpret_cast<const bf16x8*>(pw + l31 * 64 + (((step * 2 + h) ^ (l31 & 7)) << 3));
        // ---- O^T += V^T P^T : tile dt covers d = dt*32 + C-rows, q col = l31 ----
        #pragma unroll
        for (int dt = 0; dt < 4; dt++) {
            const unsigned short* vrow = vb + (dt * 32 + l31) * 64;
            #pragma unroll
            for (int step = 0; step < 4; step++) {
                bf16x8 vf = *reinterpret_cast<const bf16x8*>(vrow + (((step * 2 + h) ^ (l31 & 7)) << 3));
                o_acc[dt] = __builtin_amdgcn_mfma_f32_32x32x16_bf16(vf, pb[step], o_acc[dt], 0, 0, 0);
            }
        }
        // no trailing barrier: next iteration's barrier protects buffer reuse
    }
    // lanes L and L+32 share q; combine their kv-halves
    lsum += __shfl_xor(lsum, 32);

    float* op = Opart + (size_t)sp * QKV_ELEMS;
    int qrow_g = b * NL + m0 + l31;
    if (lane < 32) lbuf[(size_t)sp * NROWS + qrow_g] = lsum;
    // O^T C-layout: d = dt*32 + (reg&3) + 8*(reg>>2) + 4*h, q = l31 -> 16 f32x4 stores
    #pragma unroll
    for (int dt = 0; dt < 4; dt++) {
        #pragma unroll
        for (int g = 0; g < 4; g++) {
            f32x4 v4 = { o_acc[dt][g * 4 + 0], o_acc[dt][g * 4 + 1],
                         o_acc[dt][g * 4 + 2], o_acc[dt][g * 4 + 3] };
            *reinterpret_cast<f32x4*>(op + (size_t)qrow_g * ND + dt * 32 + g * 8 + h * 4) = v4;
        }
    }
}

// merge S split partials (fixed-M: plain sums) -> normalized out (f32)
__global__ __launch_bounds__(256) void attn_merge(const float* __restrict__ Opart,
                                                  const float* __restrict__ lbuf,
                                                  float* __restrict__ out, int S) {
    int idx = blockIdx.x * 256 + threadIdx.x;   // one float4 group
    int row = idx >> 5;
    int dg = (idx & 31) * 4;
    float L = 0.f;
    float4 acc = make_float4(0.f, 0.f, 0.f, 0.f);
    for (int s = 0; s < S; s++) {
        L += lbuf[(size_t)s * NROWS + row];
        float4 o = *reinterpret_cast<const float4*>(Opart + (size_t)s * QKV_ELEMS + (size_t)row * ND + dg);
        acc.x += o.x; acc.y += o.y; acc.z += o.z; acc.w += o.w;
    }
    float inv = 1.0f / L;
    float4 res = make_float4(acc.x * inv, acc.y * inv, acc.z * inv, acc.w * inv);
    *reinterpret_cast<float4*>(out + (size_t)row * ND + dg) = res;
}

extern "C" void kernel_launch(void* const* d_in, const int* in_sizes, int n_in,
                              void* d_out, int out_size, void* d_ws, size_t ws_size,
                              hipStream_t stream) {
    const float* x_inner = (const float*)d_in[0];
    const float* x_outer = (const float*)d_in[1];
    const float* Wq = (const float*)d_in[2];
    const float* bq = (const float*)d_in[3];
    const float* Wk = (const float*)d_in[4];
    const float* bk = (const float*)d_in[5];
    const float* Wv = (const float*)d_in[6];
    const float* bv = (const float*)d_in[7];
    float* out = (float*)d_out;

    // workspace: [ union { Opart, l } ][ Qb ][ Kb ][ Vtb ][ Wall ]
    size_t need4 = 34078720u + 3 * QKV_ELEMS * 2 + 3 * W_ELEMS * 2;
    int S = (ws_size >= need4) ? 4 : 2;
    size_t union_bytes = (S == 4) ? 34078720u : 17039360u;

    char* w = (char*)d_ws;
    float* Opart = (float*)w;                                // [S][B*L][D]
    float* lbuf = (float*)(w + (size_t)S * QKV_ELEMS * 4);   // [S][B*L]
    unsigned short* Qb = (unsigned short*)(w + union_bytes); // [B,L,D]
    unsigned short* Kb = Qb + QKV_ELEMS;                     // [B,L,D]
    unsigned short* Vtb = Kb + QKV_ELEMS;                    // [B,D,L]
    unsigned short* Wall = Vtb + QKV_ELEMS;                  // [3][D][C]

    cast_w3<<<(3 * W_ELEMS + 255) / 256, 256, 0, stream>>>(Wq, Wk, Wv, Wall);
    dim3 pgrid(NB * (NL / 64), 3);
    proj_direct<<<pgrid, 256, 0, stream>>>(x_inner, x_outer, Wall, bq, bk, bv, Qb, Kb, Vtb);
    dim3 fgrid(NB * (NL / 128), S);
    flash_attn_split<<<fgrid, 256, 0, stream>>>(Qb, Kb, Vtb, Opart, lbuf, NL / S);
    attn_merge<<<(NROWS * ND / 4 + 255) / 256, 256, 0, stream>>>(Opart, lbuf, out, S);
}